// Round 19
// baseline (107.816 us; speedup 1.0000x reference)
//
#include <hip/hip_runtime.h>

// Output = jacobi(X, Mask1, 100) — the multigrid sweeps in the reference are
// dead code for the returned value (grids[0] is never mutated).
//
// Trapezoidal temporal blocking, register-resident (10 launches x TI=10,
// 128x64 tile, 512 threads, 4x4 cells/thread, 240 blocks = 1/CU).
//
// r19 change: NO __syncthreads in the iteration loop. Communication audit:
// horizontal L/R strips are strictly INTRA-wave (pc+-1 = lane+-1; pc=0/31
// read zeroed guard cols); vertical intra-pair is permlane (registers);
// only the T/B strips cross waves — and only to wid+-1. So the full-block
// barrier convoy (~1000 cyc/iter with 2 waves/SIMD) is replaced by per-wave
// monotonic flags in LDS with WORKGROUP-scope acquire/release atomics
// (ds ops + lgkmcnt — NOT the agent-scope buffer_inv storm of r8/r9).
//
// Protocol: flag[w] = number of edge-sets wave w has published (initial
// publish => 0 ... set before the single prologue barrier). Iter j:
//   wait flag[w-1]>=j && flag[w+1]>=j  -> edges for iter j readable
//   read buf[j&1] halos; compute; publish into buf[(j+1)&1];
//   lane0: release-store flag[w]=j+1  (lgkmcnt(0) first: orders ALL the
//   wave's ds reads+writes before the flag becomes visible)
// Overwrite safety: publishing iter j+1 edges overwrites iter j-1's slot;
// neighbor having flag>=j implies it finished iter j-1 INCLUDING its halo
// reads (release waits on reads too), so no race. Neighbor can't clobber
// what we read at iter j: it needs our flag>=j+1, set only after our reads
// completed. Waves pipeline with +-1 skew instead of convoying.
//
// Tile edges compute bounded garbage that never reaches the valid window
// (light-cone: HX=12 > TI-1, TI rows); exterior cells stay 0 via mask=0.

#define W 1024
#define H 1024
#define TILE_W 128
#define TILE_H 64
#define TI 10                    // fused iterations per launch
#define OS_X 104                 // valid cols per tile: [12, 116)
#define OS_Y 44                  // valid rows per tile: [10, 54)
#define HX 12                    // left col halo (>= TI, keeps 16B alignment)
#define NBX 10                   // 10*104 = 1040 >= 1024
#define NBY 24                   // 24*44  = 1056 >= 1024
#define NLAUNCH 10               // NLAUNCH * TI = 100
#define FBIG 0x3fffffff

typedef unsigned uint2v __attribute__((ext_vector_type(2)));

__device__ __forceinline__ float4 ld4(const float* __restrict__ p, int gr, int gc) {
    // gc is a multiple of 4 and W%4==0 -> the quad is entirely in or out
    if ((unsigned)gr < (unsigned)H && (unsigned)gc < (unsigned)W)
        return *(const float4*)&p[gr * W + gc];
    return make_float4(0.f, 0.f, 0.f, 0.f);
}

__device__ __forceinline__ float4 rowstep(const float4 up, const float4 ce,
                                          const float4 dn, const float lf,
                                          const float rt, const float4 m) {
    float4 s, n;
    s.x = (up.x + dn.x) + (lf   + ce.y);
    s.y = (up.y + dn.y) + (ce.x + ce.z);
    s.z = (up.z + dn.z) + (ce.y + ce.w);
    s.w = (up.w + dn.w) + (ce.z + rt);
    n.x = fmaf(m.x, fmaf(0.25f, s.x, -ce.x), ce.x);
    n.y = fmaf(m.y, fmaf(0.25f, s.y, -ce.y), ce.y);
    n.z = fmaf(m.z, fmaf(0.25f, s.z, -ce.z), ce.z);
    n.w = fmaf(m.w, fmaf(0.25f, s.w, -ce.w), ce.w);
    return n;
}

// lane l <-> lane l^32 exchange of p, robust to permlane32_swap convention:
// r holds {own p, partner p} in SOME order per lane -> XOR recovers partner.
__device__ __forceinline__ float xchg32(float p) {
    unsigned u = __float_as_uint(p);
    uint2v r = __builtin_amdgcn_permlane32_swap(u, u, false, false);
    return __uint_as_float(r.x ^ r.y ^ u);
}

__device__ __forceinline__ float4 xchg32_4(const float4 p) {
    return make_float4(xchg32(p.x), xchg32(p.y), xchg32(p.z), xchg32(p.w));
}

__device__ __forceinline__ float4 sel4(bool c, const float4 a, const float4 b) {
    return make_float4(c ? a.x : b.x, c ? a.y : b.y,
                       c ? a.z : b.z, c ? a.w : b.w);
}

__shared__ float4 SLs[2][18][34];   // left-col packs  (+ col guards)
__shared__ float4 SRs[2][18][34];   // right-col packs
__shared__ float4 STs[2][10][32];   // wave top rows   (+ row guard)
__shared__ float4 SBs[2][10][32];   // wave bottom rows
__shared__ int    wflag[10];        // [0]=.[9]=BIG guards, [w+1]=wave w

// One Jacobi iteration; RB/PUB compile-time -> immediate LDS offsets.
template <int RB, bool PUB>
__device__ __forceinline__ void one_iter(
    int j, int pr, int pc, int wid, int lane, bool lowHalf,
    float4 (&c)[4], const float4 (&m)[4])
{
    // wait for neighbor waves' edges for iter j (usually already there)
    while (__hip_atomic_load(&wflag[wid], __ATOMIC_ACQUIRE,
                             __HIP_MEMORY_SCOPE_WORKGROUP) < j ||
           __hip_atomic_load(&wflag[wid + 2], __ATOMIC_ACQUIRE,
                             __HIP_MEMORY_SCOPE_WORKGROUP) < j) {}

    // vertical intra-wave exchange (VALU): partner's boundary row
    const float4 p4 = sel4(lowHalf, c[3], c[0]);
    const float4 q4 = xchg32_4(p4);

    // vertical cross-wave: half-exec masked loads merge into q4 copies
    float4 th = q4, bh = q4;
    if (lowHalf) th = SBs[RB][wid][pc];           // wave above's bottom row
    else         bh = STs[RB][wid + 2][pc];       // wave below's top row

    // horizontal via LDS strips (intra-wave), direct indexing
    const float4 lh = SRs[RB][pr + 1][pc];        // left's right col
    const float4 rh = SLs[RB][pr + 1][pc + 2];    // right's left col

    const float4 n0 = rowstep(th,   c[0], c[1], lh.x, rh.x, m[0]);
    const float4 n1 = rowstep(c[0], c[1], c[2], lh.y, rh.y, m[1]);
    const float4 n2 = rowstep(c[1], c[2], c[3], lh.z, rh.z, m[2]);
    const float4 n3 = rowstep(c[2], c[3], bh,   lh.w, rh.w, m[3]);
    c[0] = n0; c[1] = n1; c[2] = n2; c[3] = n3;

    if (PUB) {
        constexpr int WB = RB ^ 1;
        SLs[WB][pr + 1][pc + 1] = make_float4(n0.x, n1.x, n2.x, n3.x);
        SRs[WB][pr + 1][pc + 1] = make_float4(n0.w, n1.w, n2.w, n3.w);
        if (lowHalf) STs[WB][wid + 1][pc] = n0;
        else         SBs[WB][wid + 1][pc] = n3;
        if (lane == 0)   // release: lgkmcnt(0) orders all wave DS ops first
            __hip_atomic_store(&wflag[wid + 1], j + 1, __ATOMIC_RELEASE,
                               __HIP_MEMORY_SCOPE_WORKGROUP);
    }
}

__global__ __launch_bounds__(512, 1) void jacobi_trap(
    const float* __restrict__ xin, const float* __restrict__ mask,
    float* __restrict__ xout)
{
    const int tid = threadIdx.x;
    const int pr  = tid >> 5;              // 0..15
    const int pc  = tid & 31;              // 0..31
    const int wid = tid >> 6;              // wave 0..7
    const int lane = tid & 63;
    const bool lowHalf = (tid & 32) == 0;  // lanes<32 = upper patch (pr even)
    const int gx0 = (int)blockIdx.x * OS_X - HX;
    const int gy0 = (int)blockIdx.y * OS_Y - TI;
    const int gr0 = gy0 + pr * 4;
    const int gc0 = gx0 + pc * 4;          // multiple of 4

    // cells + mask -> registers first (global loads in flight early)
    float4 c[4], m[4];
    #pragma unroll
    for (int i = 0; i < 4; ++i) {
        c[i] = ld4(xin,  gr0 + i, gc0);
        m[i] = ld4(mask, gr0 + i, gc0);
    }

    // zero ONLY the read guards; init flags (guards = BIG, waves = 0)
    const float4 z4 = make_float4(0.f, 0.f, 0.f, 0.f);
    if (tid < 72) {
        int b = tid / 36, r2 = tid % 36;
        if (r2 < 18) SRs[b][r2][0] = z4;
        else         SLs[b][r2 - 18][33] = z4;
    } else if (tid >= 128 && tid < 256) {
        int j = tid - 128, b = j >> 6, r3 = j & 63;
        if (r3 < 32) STs[b][9][r3] = z4;
        else         SBs[b][0][r3 - 32] = z4;
    } else if (tid >= 256 && tid < 266) {
        int f = tid - 256;
        wflag[f] = (f == 0 || f == 9) ? FBIG : 0;
    }

    // publish initial edges into buffer 0 (disjoint from guard ring)
    SLs[0][pr + 1][pc + 1] = make_float4(c[0].x, c[1].x, c[2].x, c[3].x);
    SRs[0][pr + 1][pc + 1] = make_float4(c[0].w, c[1].w, c[2].w, c[3].w);
    if (lowHalf) STs[0][wid + 1][pc] = c[0];
    else         SBs[0][wid + 1][pc] = c[3];
    __syncthreads();   // ONLY barrier: flags + iter-0 edges visible

    // fully unrolled TI=10, flag-synced; last iter skips publish
    one_iter<0, true >(0, pr, pc, wid, lane, lowHalf, c, m);
    one_iter<1, true >(1, pr, pc, wid, lane, lowHalf, c, m);
    one_iter<0, true >(2, pr, pc, wid, lane, lowHalf, c, m);
    one_iter<1, true >(3, pr, pc, wid, lane, lowHalf, c, m);
    one_iter<0, true >(4, pr, pc, wid, lane, lowHalf, c, m);
    one_iter<1, true >(5, pr, pc, wid, lane, lowHalf, c, m);
    one_iter<0, true >(6, pr, pc, wid, lane, lowHalf, c, m);
    one_iter<1, true >(7, pr, pc, wid, lane, lowHalf, c, m);
    one_iter<0, true >(8, pr, pc, wid, lane, lowHalf, c, m);
    one_iter<1, false>(9, pr, pc, wid, lane, lowHalf, c, m);

    // store valid window: rows [TI, TILE_H-TI), cols [HX, HX+OS_X)
    const int lc = pc * 4;
    if (lc >= HX && lc < HX + OS_X && (unsigned)gc0 < (unsigned)W) {
        #pragma unroll
        for (int i = 0; i < 4; ++i) {
            int lr = pr * 4 + i;
            if (lr < TI || lr >= TILE_H - TI) continue;
            int gr = gy0 + lr;
            if ((unsigned)gr >= (unsigned)H) continue;
            *(float4*)&xout[gr * W + gc0] = c[i];
        }
    }
}

extern "C" void kernel_launch(void* const* d_in, const int* in_sizes, int n_in,
                              void* d_out, int out_size, void* d_ws, size_t ws_size,
                              hipStream_t stream) {
    const float* X = (const float*)d_in[0];   // (1,1,1024,1024)
    const float* M = (const float*)d_in[1];   // Mask1
    float* out = (float*)d_out;
    float* ws  = (float*)d_ws;                // 4 MB ping buffer

    dim3 grid(NBX, NBY), block(512);
    // l=0: X->ws; alternate; l=9 (odd) -> out. Valid-window union covers
    // the full domain, so ws/out are fully written before any read.
    const float* src = X;
    for (int l = 0; l < NLAUNCH; ++l) {
        float* dst = (l & 1) ? out : ws;
        jacobi_trap<<<grid, block, 0, stream>>>(src, M, dst);
        src = dst;
    }
}

// Round 20
// 92.765 us; speedup vs baseline: 1.1622x; 1.1622x over previous
//
#include <hip/hip_runtime.h>

// Output = jacobi(X, Mask1, 100) — the multigrid sweeps in the reference are
// dead code for the returned value (grids[0] is never mutated).
//
// Trapezoidal temporal blocking, register-resident (10 launches x TI=10,
// 128x64 tile, 512 threads, 4x4 cells/thread, 240 blocks = 1/CU).
// r20 = r18 (best, 101.1us) + two latency micro-opts:
//  (a) one_iter reordered: LDS reads issued first, boundary rows n0/n3
//      computed and their half-exec T/B publishes issued BEFORE interior
//      rows n1/n2 -> ds_writes drain under interior compute, shorter path
//      into the barrier.
//  (b) chunked XCD swizzle (T1 adapted): 1-D 240-block grid, logical =
//      (d&7)*30 + (d>>3). 30 consecutive logical blocks share an XCD and
//      the mapping is launch-stable, so (i) launch-(l) producer and
//      launch-(l+1) consumer of a tile sit on the same XCD and (ii)
//      x/y-neighbor blocks (halo apron reads, ~40% of prologue traffic)
//      are mostly same-XCD -> local L2 instead of cross-XCD L3.
// Proven pieces kept: permlane32_swap XOR identity (interpretation-proof),
// half-exec T/B strips, direct LDS indexing (no pointer selects - r15),
// no DPP (r16), hardware barrier (r19 flags were worse), full unroll (r18).
//
// Tile edges compute bounded garbage that never reaches the valid window
// (light-cone: HX=12 > TI-1, TI rows); exterior cells stay 0 via mask=0.

#define W 1024
#define H 1024
#define TILE_W 128
#define TILE_H 64
#define TI 10                    // fused iterations per launch
#define OS_X 104                 // valid cols per tile: [12, 116)
#define OS_Y 44                  // valid rows per tile: [10, 54)
#define HX 12                    // left col halo (>= TI, keeps 16B alignment)
#define NBX 10                   // 10*104 = 1040 >= 1024
#define NBY 24                   // 24*44  = 1056 >= 1024
#define NBLK (NBX * NBY)         // 240 = 8 XCDs x 30
#define NLAUNCH 10               // NLAUNCH * TI = 100

typedef unsigned uint2v __attribute__((ext_vector_type(2)));

__device__ __forceinline__ float4 ld4(const float* __restrict__ p, int gr, int gc) {
    // gc is a multiple of 4 and W%4==0 -> the quad is entirely in or out
    if ((unsigned)gr < (unsigned)H && (unsigned)gc < (unsigned)W)
        return *(const float4*)&p[gr * W + gc];
    return make_float4(0.f, 0.f, 0.f, 0.f);
}

__device__ __forceinline__ float4 rowstep(const float4 up, const float4 ce,
                                          const float4 dn, const float lf,
                                          const float rt, const float4 m) {
    float4 s, n;
    s.x = (up.x + dn.x) + (lf   + ce.y);
    s.y = (up.y + dn.y) + (ce.x + ce.z);
    s.z = (up.z + dn.z) + (ce.y + ce.w);
    s.w = (up.w + dn.w) + (ce.z + rt);
    n.x = fmaf(m.x, fmaf(0.25f, s.x, -ce.x), ce.x);
    n.y = fmaf(m.y, fmaf(0.25f, s.y, -ce.y), ce.y);
    n.z = fmaf(m.z, fmaf(0.25f, s.z, -ce.z), ce.z);
    n.w = fmaf(m.w, fmaf(0.25f, s.w, -ce.w), ce.w);
    return n;
}

// lane l <-> lane l^32 exchange of p, robust to permlane32_swap convention:
// r holds {own p, partner p} in SOME order per lane -> XOR recovers partner.
__device__ __forceinline__ float xchg32(float p) {
    unsigned u = __float_as_uint(p);
    uint2v r = __builtin_amdgcn_permlane32_swap(u, u, false, false);
    return __uint_as_float(r.x ^ r.y ^ u);
}

__device__ __forceinline__ float4 xchg32_4(const float4 p) {
    return make_float4(xchg32(p.x), xchg32(p.y), xchg32(p.z), xchg32(p.w));
}

__device__ __forceinline__ float4 sel4(bool c, const float4 a, const float4 b) {
    return make_float4(c ? a.x : b.x, c ? a.y : b.y,
                       c ? a.z : b.z, c ? a.w : b.w);
}

__shared__ float4 SLs[2][18][34];   // left-col packs  (+ col guards)
__shared__ float4 SRs[2][18][34];   // right-col packs
__shared__ float4 STs[2][10][32];   // wave top rows   (+ row guard)
__shared__ float4 SBs[2][10][32];   // wave bottom rows

// One Jacobi iteration; RB/PUB compile-time -> immediate LDS offsets.
// Reordered: reads -> permlane -> boundary rows -> T/B publish -> interior
// rows -> L/R publish -> barrier.
template <int RB, bool PUB>
__device__ __forceinline__ void one_iter(
    int pr, int pc, int wid, bool lowHalf,
    float4 (&c)[4], const float4 (&m)[4])
{
    // issue all LDS reads up front
    const float4 lh = SRs[RB][pr + 1][pc];        // left's right col
    const float4 rh = SLs[RB][pr + 1][pc + 2];    // right's left col
    float4 th, bh;                                 // merged below
    // vertical intra-wave exchange (VALU) overlaps the reads
    const float4 p4 = sel4(lowHalf, c[3], c[0]);
    const float4 q4 = xchg32_4(p4);
    th = q4; bh = q4;
    if (lowHalf) th = SBs[RB][wid][pc];           // wave above's bottom row
    else         bh = STs[RB][wid + 2][pc];       // wave below's top row

    // boundary rows first -> their publishes issue early
    const float4 n0 = rowstep(th,   c[0], c[1], lh.x, rh.x, m[0]);
    const float4 n3 = rowstep(c[2], c[3], bh,   lh.w, rh.w, m[3]);
    if (PUB) {
        constexpr int WB = RB ^ 1;
        if (lowHalf) STs[WB][wid + 1][pc] = n0;
        else         SBs[WB][wid + 1][pc] = n3;
    }

    // interior rows while the T/B writes drain
    const float4 n1 = rowstep(c[0], c[1], c[2], lh.y, rh.y, m[1]);
    const float4 n2 = rowstep(c[1], c[2], c[3], lh.z, rh.z, m[2]);

    if (PUB) {
        constexpr int WB = RB ^ 1;
        SLs[WB][pr + 1][pc + 1] = make_float4(n0.x, n1.x, n2.x, n3.x);
        SRs[WB][pr + 1][pc + 1] = make_float4(n0.w, n1.w, n2.w, n3.w);
    }
    c[0] = n0; c[1] = n1; c[2] = n2; c[3] = n3;
    if (PUB) __syncthreads();
}

__global__ __launch_bounds__(512, 1) void jacobi_trap(
    const float* __restrict__ xin, const float* __restrict__ mask,
    float* __restrict__ xout)
{
    const int tid = threadIdx.x;
    const int pr  = tid >> 5;              // 0..15
    const int pc  = tid & 31;              // 0..31
    const int wid = tid >> 6;              // wave 0..7
    const bool lowHalf = (tid & 32) == 0;  // lanes<32 = upper patch (pr even)

    // chunked XCD swizzle: dispatch d -> logical block; 30 consecutive
    // logical blocks share one XCD (d%8), mapping identical every launch.
    const int d = (int)blockIdx.x;
    const int logical = (d & 7) * 30 + (d >> 3);
    const int bx = logical % NBX;
    const int by = logical / NBX;

    const int gx0 = bx * OS_X - HX;
    const int gy0 = by * OS_Y - TI;
    const int gr0 = gy0 + pr * 4;
    const int gc0 = gx0 + pc * 4;          // multiple of 4

    // cells + mask -> registers first (global loads in flight early)
    float4 c[4], m[4];
    #pragma unroll
    for (int i = 0; i < 4; ++i) {
        c[i] = ld4(xin,  gr0 + i, gc0);
        m[i] = ld4(mask, gr0 + i, gc0);
    }

    // zero ONLY the read guards (deterministic, NaN-free halos):
    // SRs col 0, SLs col 33 (rows 0..17, both bufs); STs row 9, SBs row 0.
    const float4 z4 = make_float4(0.f, 0.f, 0.f, 0.f);
    if (tid < 72) {
        int b = tid / 36, r2 = tid % 36;
        if (r2 < 18) SRs[b][r2][0] = z4;
        else         SLs[b][r2 - 18][33] = z4;
    } else if (tid >= 128 && tid < 256) {
        int j = tid - 128, b = j >> 6, r3 = j & 63;
        if (r3 < 32) STs[b][9][r3] = z4;
        else         SBs[b][0][r3 - 32] = z4;
    }

    // publish initial edges into buffer 0 (disjoint from guard ring)
    SLs[0][pr + 1][pc + 1] = make_float4(c[0].x, c[1].x, c[2].x, c[3].x);
    SRs[0][pr + 1][pc + 1] = make_float4(c[0].w, c[1].w, c[2].w, c[3].w);
    if (lowHalf) STs[0][wid + 1][pc] = c[0];
    else         SBs[0][wid + 1][pc] = c[3];
    __syncthreads();

    // fully unrolled TI=10: rb = 0,1,0,1,... ; last iter skips publish
    one_iter<0, true >(pr, pc, wid, lowHalf, c, m);
    one_iter<1, true >(pr, pc, wid, lowHalf, c, m);
    one_iter<0, true >(pr, pc, wid, lowHalf, c, m);
    one_iter<1, true >(pr, pc, wid, lowHalf, c, m);
    one_iter<0, true >(pr, pc, wid, lowHalf, c, m);
    one_iter<1, true >(pr, pc, wid, lowHalf, c, m);
    one_iter<0, true >(pr, pc, wid, lowHalf, c, m);
    one_iter<1, true >(pr, pc, wid, lowHalf, c, m);
    one_iter<0, true >(pr, pc, wid, lowHalf, c, m);
    one_iter<1, false>(pr, pc, wid, lowHalf, c, m);

    // store valid window: rows [TI, TILE_H-TI), cols [HX, HX+OS_X)
    const int lc = pc * 4;
    if (lc >= HX && lc < HX + OS_X && (unsigned)gc0 < (unsigned)W) {
        #pragma unroll
        for (int i = 0; i < 4; ++i) {
            int lr = pr * 4 + i;
            if (lr < TI || lr >= TILE_H - TI) continue;
            int gr = gy0 + lr;
            if ((unsigned)gr >= (unsigned)H) continue;
            *(float4*)&xout[gr * W + gc0] = c[i];
        }
    }
}

extern "C" void kernel_launch(void* const* d_in, const int* in_sizes, int n_in,
                              void* d_out, int out_size, void* d_ws, size_t ws_size,
                              hipStream_t stream) {
    const float* X = (const float*)d_in[0];   // (1,1,1024,1024)
    const float* M = (const float*)d_in[1];   // Mask1
    float* out = (float*)d_out;
    float* ws  = (float*)d_ws;                // 4 MB ping buffer

    dim3 grid(NBLK), block(512);
    // l=0: X->ws; alternate; l=9 (odd) -> out. Valid-window union covers
    // the full domain, so ws/out are fully written before any read.
    const float* src = X;
    for (int l = 0; l < NLAUNCH; ++l) {
        float* dst = (l & 1) ? out : ws;
        jacobi_trap<<<grid, block, 0, stream>>>(src, M, dst);
        src = dst;
    }
}